// Round 15
// baseline (317.010 us; speedup 1.0000x reference)
//
#include <hip/hip_runtime.h>
#include <hip/hip_fp16.h>

// ---------------------------------------------------------------------------
// SE3Transformer block. Round 15: R14 (best-known 311us) + three refinements:
//   1. Ut fused into Um node block (1024B rows + 64B f32 tail, stride 1088B):
//      edge kernels gather ONE region per src instead of two arrays.
//   2. fuse1 count role: 2 edges/thread (4 atomics in flight, fewer blocks).
//   3. fuse3 interleaved (u2-L0 every 3rd slot among prep blocks) — ranges
//      pipeline, interleave makes them concurrent (same fix as fuse1 in R14).
// Kept: interleaved count in fuse1, fuse2 (scan||embed2), separate
// reduce0 + u2-L1 (R13's fusion lost occupancy), LN tree-reduce, fdot2
// GEMM+contraction, src-sorted traversal -> dst-sorted msg scatter.
// ---------------------------------------------------------------------------

#define Y0C 0.28209479177387814f
#define C1C 0.4886025119029199f

typedef _Float16 hv2 __attribute__((ext_vector_type(2)));

#if defined(__has_builtin)
#if __has_builtin(__builtin_amdgcn_fdot2)
#define FDOT2(a, b, c) __builtin_amdgcn_fdot2((a), (b), (c), false)
#endif
#endif
#ifndef FDOT2
#define FDOT2(a, b, c) ((c) + (float)(a).x * (float)(b).x + (float)(a).y * (float)(b).y)
#endif

static __device__ __forceinline__ unsigned h2u(__half2 h) {
    union { __half2 h; unsigned u; } x; x.h = h; return x.u;
}
static __device__ __forceinline__ __half2 u2h(unsigned u) {
    union { unsigned u; __half2 h; } x; x.u = u; return x.h;
}
static __device__ __forceinline__ hv2 u2hv(unsigned u) {
    union { unsigned u; hv2 h; } x; x.u = u; return x.h;
}
static __device__ __forceinline__ unsigned hv2u(hv2 h) {
    union { hv2 h; unsigned u; } x; x.h = h; return x.u;
}
static __device__ __forceinline__ hv2 f2hv(float a, float b) {
    hv2 r; r.x = (_Float16)a; r.y = (_Float16)b; return r;
}
static __device__ __forceinline__ float hbits2f(unsigned short s) {
    __half_raw r; r.x = s; return __half2float((__half)r);
}

struct RadialW {
    const float *W1, *b1, *g1, *gb1, *b2, *g2, *gb2;
    const unsigned* W2q;   // packed [j*16+kp] = half2(W2[2kp][j], W2[2kp+1][j])
};

// radial MLP: (x0,x1,x2) -> 32 (LN,relu) -> [fdot2 GEMM] -> 32 (LN,relu)
__device__ __forceinline__ void radial_net_pk(float x0, float x1, float x2,
                                              RadialW rw, hv2* hvpk /*[16]*/) {
    float h[32];
#pragma unroll
    for (int j = 0; j < 32; ++j)
        h[j] = rw.b1[j] + x0 * rw.W1[j] + x1 * rw.W1[32 + j] + x2 * rw.W1[64 + j];
    float s0 = 0.f, s1 = 0.f, s2 = 0.f, s3 = 0.f;
#pragma unroll
    for (int p = 0; p < 8; ++p) {
        s0 += h[4 * p]; s1 += h[4 * p + 1]; s2 += h[4 * p + 2]; s3 += h[4 * p + 3];
    }
    float mu = ((s0 + s1) + (s2 + s3)) * 0.03125f;
    float v0 = 0.f, v1 = 0.f, v2 = 0.f, v3 = 0.f;
#pragma unroll
    for (int p = 0; p < 8; ++p) {
        float d0 = h[4 * p] - mu, d1 = h[4 * p + 1] - mu;
        float d2 = h[4 * p + 2] - mu, d3 = h[4 * p + 3] - mu;
        v0 = fmaf(d0, d0, v0); v1 = fmaf(d1, d1, v1);
        v2 = fmaf(d2, d2, v2); v3 = fmaf(d3, d3, v3);
    }
    float var = ((v0 + v1) + (v2 + v3)) * 0.03125f;
    float rs = rsqrtf(var + 1e-5f);
#pragma unroll
    for (int j = 0; j < 32; ++j)
        h[j] = fmaxf((h[j] - mu) * rs * rw.g1[j] + rw.gb1[j], 0.f);

    hv2 hp[16];
#pragma unroll
    for (int p = 0; p < 16; ++p) hp[p] = f2hv(h[2 * p], h[2 * p + 1]);

    float h2[32];
#pragma unroll
    for (int j = 0; j < 32; ++j) {
        float acc = rw.b2[j];
        const unsigned* __restrict__ wj = rw.W2q + j * 16;   // uniform -> s_load
#pragma unroll
        for (int kp = 0; kp < 16; ++kp)
            acc = FDOT2(hp[kp], u2hv(wj[kp]), acc);
        h2[j] = acc;
    }
    s0 = s1 = s2 = s3 = 0.f;
#pragma unroll
    for (int p = 0; p < 8; ++p) {
        s0 += h2[4 * p]; s1 += h2[4 * p + 1]; s2 += h2[4 * p + 2]; s3 += h2[4 * p + 3];
    }
    mu = ((s0 + s1) + (s2 + s3)) * 0.03125f;
    v0 = v1 = v2 = v3 = 0.f;
#pragma unroll
    for (int p = 0; p < 8; ++p) {
        float d0 = h2[4 * p] - mu, d1 = h2[4 * p + 1] - mu;
        float d2 = h2[4 * p + 2] - mu, d3 = h2[4 * p + 3] - mu;
        v0 = fmaf(d0, d0, v0); v1 = fmaf(d1, d1, v1);
        v2 = fmaf(d2, d2, v2); v3 = fmaf(d3, d3, v3);
    }
    var = ((v0 + v1) + (v2 + v3)) * 0.03125f;
    rs = rsqrtf(var + 1e-5f);
    float y[32];
#pragma unroll
    for (int j = 0; j < 32; ++j)
        y[j] = fmaxf((h2[j] - mu) * rs * rw.g2[j] + rw.gb2[j], 0.f);
#pragma unroll
    for (int p = 0; p < 16; ++p) hvpk[p] = f2hv(y[2 * p], y[2 * p + 1]);
}

// v[o] = Ut[o] + sum_p dot2(hvpk[p], Um[o][p])
// Up = node block: 256 unsigned (16 o-rows of f16 pairs) + 16 f32 tail.
__device__ __forceinline__ void contract_dot(const hv2* hvpk,
                                             const unsigned* __restrict__ Up,
                                             float* v /*[16]*/) {
    const uint4* __restrict__ Um = (const uint4*)Up;
    const float* __restrict__ Ut = (const float*)(Up + 256);
    float4 t0 = ((const float4*)Ut)[0];
    float4 t1 = ((const float4*)Ut)[1];
    float4 t2 = ((const float4*)Ut)[2];
    float4 t3 = ((const float4*)Ut)[3];
    float tail[16] = {t0.x, t0.y, t0.z, t0.w, t1.x, t1.y, t1.z, t1.w,
                      t2.x, t2.y, t2.z, t2.w, t3.x, t3.y, t3.z, t3.w};
#pragma unroll
    for (int o = 0; o < 16; ++o) {
        uint4 q0 = Um[o * 4];
        uint4 q1 = Um[o * 4 + 1];
        uint4 q2 = Um[o * 4 + 2];
        uint4 q3 = Um[o * 4 + 3];
        float acc = tail[o];
        acc = FDOT2(hvpk[0],  u2hv(q0.x), acc);
        acc = FDOT2(hvpk[1],  u2hv(q0.y), acc);
        acc = FDOT2(hvpk[2],  u2hv(q0.z), acc);
        acc = FDOT2(hvpk[3],  u2hv(q0.w), acc);
        acc = FDOT2(hvpk[4],  u2hv(q1.x), acc);
        acc = FDOT2(hvpk[5],  u2hv(q1.y), acc);
        acc = FDOT2(hvpk[6],  u2hv(q1.z), acc);
        acc = FDOT2(hvpk[7],  u2hv(q1.w), acc);
        acc = FDOT2(hvpk[8],  u2hv(q2.x), acc);
        acc = FDOT2(hvpk[9],  u2hv(q2.y), acc);
        acc = FDOT2(hvpk[10], u2hv(q2.z), acc);
        acc = FDOT2(hvpk[11], u2hv(q2.w), acc);
        acc = FDOT2(hvpk[12], u2hv(q3.x), acc);
        acc = FDOT2(hvpk[13], u2hv(q3.y), acc);
        acc = FDOT2(hvpk[14], u2hv(q3.z), acc);
        acc = FDOT2(hvpk[15], u2hv(q3.w), acc);
        v[o] = acc;
    }
}

// ---- fuse1: embed1 || pack || count2 (interleaved, 2 edges/thread) --------
__global__ __launch_bounds__(256) void k_fuse1(
    const float* __restrict__ nf, const float* __restrict__ W1,
    const float* __restrict__ b1, float* __restrict__ t, int N,
    int nbC, int nbEmb,
    const float* __restrict__ rW3, const float* __restrict__ rW2,
    unsigned* __restrict__ Wp, unsigned* __restrict__ Wq,
    const int* __restrict__ src, const int* __restrict__ dst,
    int* __restrict__ cntd, int* __restrict__ cnts,
    int* __restrict__ posd, int* __restrict__ poss, int E) {
    int b = blockIdx.x;
    int q = b >> 2;
    bool isCount = ((b & 3) == 3) && (q < nbC);
    if (isCount) {
        // ---- count2 role: 2 strided edges, 4 atomics in flight ----
        int e0 = q * 256 + threadIdx.x;
        int e1 = e0 + nbC * 256;
        if (e0 < E) {
            posd[e0] = atomicAdd(cntd + dst[e0], 1);
            poss[e0] = atomicAdd(cnts + src[e0], 1);
        }
        if (e1 < E) {
            posd[e1] = atomicAdd(cntd + dst[e1], 1);
            poss[e1] = atomicAdd(cnts + src[e1], 1);
        }
        return;
    }
    int dense = b - min(q, nbC);   // count blocks before b
    if (dense >= nbEmb) {
        // ---- pack role ----
        int tt = (dense - nbEmb) * 256 + threadIdx.x;
        if (tt < 3 * 256) {
            int ni = tt >> 8;
            int net = (ni == 0) ? 0 : ni + 1;
            int r = tt & 255;
            int i = r >> 4, o = r & 15;
            const float* __restrict__ W3n = rW3 + (size_t)net * 8192;
            unsigned* __restrict__ dp = Wp + (size_t)ni * 4608 + (size_t)(i * 16 + o) * 18;
#pragma unroll
            for (int kp = 0; kp < 16; ++kp) {
                float a = W3n[(2 * kp) * 256 + o * 16 + i];
                float bv = W3n[(2 * kp + 1) * 256 + o * 16 + i];
                dp[kp] = h2u(__floats2half2_rn(a, bv));
            }
        } else if (tt < 3 * 256 + 3 * 512) {
            int r = tt - 3 * 256;
            int ni = r / 512;
            int net = (ni == 0) ? 0 : ni + 1;
            int jk = r - ni * 512;
            int j = jk >> 4, kp = jk & 15;
            const float* __restrict__ W2n = rW2 + (size_t)net * 1024;
            Wq[ni * 512 + j * 16 + kp] =
                h2u(__floats2half2_rn(W2n[(2 * kp) * 32 + j],
                                      W2n[(2 * kp + 1) * 32 + j]));
        }
        return;
    }
    // ---- embed1 role ----
    int idx = dense * 256 + threadIdx.x;
    if (idx >= N * 67) return;
    int n = idx / 67, j = idx - n * 67;
    const float* __restrict__ x = nf + (size_t)n * 67;
    const float* __restrict__ w = W1 + j;
    float a0 = b1[j], a1 = 0.f, a2 = 0.f, a3 = 0.f;
#pragma unroll
    for (int i = 0; i < 64; i += 4) {
        a0 = fmaf(x[i],     w[(size_t)i * 67],       a0);
        a1 = fmaf(x[i + 1], w[(size_t)(i + 1) * 67], a1);
        a2 = fmaf(x[i + 2], w[(size_t)(i + 2) * 67], a2);
        a3 = fmaf(x[i + 3], w[(size_t)(i + 3) * 67], a3);
    }
    a0 = fmaf(x[64], w[64 * 67], a0);
    a1 = fmaf(x[65], w[65 * 67], a1);
    a2 = fmaf(x[66], w[66 * 67], a2);
    float s = (a0 + a1) + (a2 + a3);
    t[idx] = (s > 0.f) ? s : expm1f(s);   // ELU(alpha=1)
}

// ---- fuse2: scan2 (blocks 0,1) || embed2 (1024-thread blocks) -------------
__global__ __launch_bounds__(1024) void k_fuse2(
    const int* __restrict__ cntd, int* __restrict__ rsd,
    const int* __restrict__ cnts, int* __restrict__ rss, int N,
    const float* __restrict__ t, const float* __restrict__ W2,
    const float* __restrict__ b2, float* __restrict__ h0) {
    if (blockIdx.x < 2) {
        const int* __restrict__ c = (blockIdx.x == 0) ? cntd : cnts;
        int* __restrict__ rs      = (blockIdx.x == 0) ? rsd  : rss;
        int chunk = (N + 1023) >> 10;
        int lo = (int)threadIdx.x * chunk;
        int sum = 0;
        for (int j = 0; j < chunk; ++j) { int i = lo + j; sum += (i < N) ? c[i] : 0; }
        __shared__ int ps[1024];
        ps[threadIdx.x] = sum;
        __syncthreads();
        for (int off = 1; off < 1024; off <<= 1) {
            int v = (threadIdx.x >= (unsigned)off) ? ps[threadIdx.x - off] : 0;
            __syncthreads();
            ps[threadIdx.x] += v;
            __syncthreads();
        }
        int run = threadIdx.x ? ps[threadIdx.x - 1] : 0;
        if (threadIdx.x == 0) rs[0] = 0;
        for (int j = 0; j < chunk; ++j) {
            int i = lo + j;
            if (i < N) { run += c[i]; rs[i + 1] = run; }
        }
        return;
    }
    int idx = (blockIdx.x - 2) * 1024 + threadIdx.x;
    if (idx >= N * 16) return;
    int n = idx >> 4, c = idx & 15;
    const float* __restrict__ x = t + (size_t)n * 67;
    const float* __restrict__ w = W2 + c;
    float a0 = b2[c], a1 = 0.f, a2 = 0.f, a3 = 0.f;
#pragma unroll
    for (int i = 0; i < 64; i += 4) {
        a0 = fmaf(x[i],     w[(size_t)i * 16],       a0);
        a1 = fmaf(x[i + 1], w[(size_t)(i + 1) * 16], a1);
        a2 = fmaf(x[i + 2], w[(size_t)(i + 2) * 16], a2);
        a3 = fmaf(x[i + 3], w[(size_t)(i + 3) * 16], a3);
    }
    a0 = fmaf(x[64], w[64 * 16], a0);
    a1 = fmaf(x[65], w[65 * 16], a1);
    a2 = fmaf(x[66], w[66 * 16], a2);
    h0[idx] = (a0 + a1) + (a2 + a3);
}

// ---- u2 body (LDS-staged packed weights, 2 nodes/thread, fused-tail) ------
__device__ __forceinline__ void u2_body(
    unsigned* WL, int nbase, const float* __restrict__ h,
    const float* __restrict__ b3, unsigned* __restrict__ Um, int N) {
    int o = threadIdx.x & 15;
    int pr = threadIdx.x >> 4;
    int n0 = nbase + pr * 2;
    int n1 = n0 + 1;
    bool ok0 = n0 < N, ok1 = n1 < N;
    int m0 = ok0 ? n0 : 0, m1 = ok1 ? n1 : 0;

    const float* __restrict__ bo = b3 + o * 16;
    float tA = 0.f, tB = 0.f;
    __half2 hhA[16], hhB[16];
    {
        const float4* hp = (const float4*)(h + (size_t)m0 * 16);
#pragma unroll
        for (int q = 0; q < 4; ++q) {
            float4 hv = hp[q];
            tA += hv.x * bo[4 * q] + hv.y * bo[4 * q + 1]
                + hv.z * bo[4 * q + 2] + hv.w * bo[4 * q + 3];
            hhA[4 * q]     = __floats2half2_rn(hv.x, hv.x);
            hhA[4 * q + 1] = __floats2half2_rn(hv.y, hv.y);
            hhA[4 * q + 2] = __floats2half2_rn(hv.z, hv.z);
            hhA[4 * q + 3] = __floats2half2_rn(hv.w, hv.w);
        }
    }
    {
        const float4* hp = (const float4*)(h + (size_t)m1 * 16);
#pragma unroll
        for (int q = 0; q < 4; ++q) {
            float4 hv = hp[q];
            tB += hv.x * bo[4 * q] + hv.y * bo[4 * q + 1]
                + hv.z * bo[4 * q + 2] + hv.w * bo[4 * q + 3];
            hhB[4 * q]     = __floats2half2_rn(hv.x, hv.x);
            hhB[4 * q + 1] = __floats2half2_rn(hv.y, hv.y);
            hhB[4 * q + 2] = __floats2half2_rn(hv.z, hv.z);
            hhB[4 * q + 3] = __floats2half2_rn(hv.w, hv.w);
        }
    }

    __half2 accA[16], accB[16];
#pragma unroll
    for (int p = 0; p < 16; ++p) {
        accA[p] = __floats2half2_rn(0.f, 0.f);
        accB[p] = __floats2half2_rn(0.f, 0.f);
    }

#pragma unroll
    for (int i = 0; i < 16; ++i) {
        const uint2* __restrict__ row = (const uint2*)(WL + i * 288 + o * 18);
        __half2 ha = hhA[i], hb = hhB[i];
#pragma unroll
        for (int q = 0; q < 8; ++q) {
            uint2 w = row[q];
            accA[2 * q]     = __hfma2(ha, u2h(w.x), accA[2 * q]);
            accA[2 * q + 1] = __hfma2(ha, u2h(w.y), accA[2 * q + 1]);
            accB[2 * q]     = __hfma2(hb, u2h(w.x), accB[2 * q]);
            accB[2 * q + 1] = __hfma2(hb, u2h(w.y), accB[2 * q + 1]);
        }
    }

    if (ok0) {
        unsigned* base = Um + (size_t)n0 * 272;
        uint4* du = (uint4*)(base + o * 16);
#pragma unroll
        for (int q = 0; q < 4; ++q)
            du[q] = make_uint4(h2u(accA[4 * q]), h2u(accA[4 * q + 1]),
                               h2u(accA[4 * q + 2]), h2u(accA[4 * q + 3]));
        ((float*)(base + 256))[o] = tA;
    }
    if (ok1) {
        unsigned* base = Um + (size_t)n1 * 272;
        uint4* du = (uint4*)(base + o * 16);
#pragma unroll
        for (int q = 0; q < 4; ++q)
            du[q] = make_uint4(h2u(accB[4 * q]), h2u(accB[4 * q + 1]),
                               h2u(accB[4 * q + 2]), h2u(accB[4 * q + 3]));
        ((float*)(base + 256))[o] = tB;
    }
}

// ---- fuse3: u2-layer0 (every 3rd slot) || prep (interleaved) --------------
__global__ __launch_bounds__(256) void k_fuse3(
    const float* __restrict__ h, const unsigned* __restrict__ Wp,
    const float* __restrict__ b3, unsigned* __restrict__ Um, int nbU, int N,
    const float* __restrict__ pos, const float* __restrict__ ew,
    const int* __restrict__ src, const int* __restrict__ dst,
    const int* __restrict__ rsd, const int* __restrict__ rss,
    const int* __restrict__ posd, const int* __restrict__ poss,
    float4* __restrict__ edgeS, uint2* __restrict__ y1d,
    int* __restrict__ s2d, int E) {
    __shared__ unsigned WL[4608];
    int b = blockIdx.x;
    int k = b / 3;
    bool isU2 = ((b % 3) == 2) && (k < nbU);
    if (isU2) {
        for (int j = threadIdx.x; j < 4608; j += 256) WL[j] = Wp[j];  // net0
        __syncthreads();
        u2_body(WL, k * 32, h, b3, Um, N);
        return;
    }
    int dense = b - min(b / 3, nbU);
    int e = dense * 256 + threadIdx.x;
    if (e >= E) return;
    int s = src[e], d = dst[e];
    float dx = pos[3 * d]     - pos[3 * s];
    float dy = pos[3 * d + 1] - pos[3 * s + 1];
    float dz = pos[3 * d + 2] - pos[3 * s + 2];
    float r = sqrtf(dx * dx + dy * dy + dz * dz);
    float im = 1.f / fmaxf(r, 1e-8f);
    int ts = rss[s] + poss[e];
    int td = rsd[d] + posd[e];
    s2d[ts] = td;
    edgeS[ts] = make_float4(ew[2 * e], ew[2 * e + 1], r, __int_as_float(s));
    y1d[td] = make_uint2(h2u(__floats2half2_rn(C1C * dy * im, C1C * dz * im)),
                         h2u(__floats2half2_rn(C1C * dx * im, 0.f)));
}

// ---- u2 standalone (layer 1, 2 nets) --------------------------------------
__global__ __launch_bounds__(256) void k_u2(
    const float* __restrict__ h, const unsigned* __restrict__ Wp,
    const float* __restrict__ b3A, const float* __restrict__ b3B,
    unsigned* __restrict__ Um0, unsigned* __restrict__ Um1,
    int wpA, int nbPerNet, int N) {
    __shared__ unsigned WL[4608];
    int netSel = blockIdx.x / nbPerNet;
    int nbase = (blockIdx.x - netSel * nbPerNet) * 32;
    const unsigned* __restrict__ g = Wp + (size_t)(wpA + netSel) * 4608;
    for (int j = threadIdx.x; j < 4608; j += 256) WL[j] = g[j];
    __syncthreads();
    u2_body(WL, nbase, h, netSel ? b3B : b3A, netSel ? Um1 : Um0, N);
}

// ---- edge kernels (src-sorted traversal, scatter-write to dst slot) -------
__global__ __launch_bounds__(256) void k_edgeL0(
    const float4* __restrict__ edgeS, const int* __restrict__ s2d, RadialW ra,
    const unsigned* __restrict__ UmA,
    unsigned short* __restrict__ msg /*stride 16*/, int E) {
    int t = blockIdx.x * blockDim.x + threadIdx.x;
    if (t >= E) return;
    float4 a = edgeS[t];
    int sn = __float_as_int(a.w);
    hv2 hv[16];
    float v[16];
    radial_net_pk(a.x, a.y, a.z, ra, hv);
    contract_dot(hv, UmA + (size_t)sn * 272, v);
    int td = s2d[t];
    uint4* m = (uint4*)(msg + (size_t)td * 16);
    m[0] = make_uint4(hv2u(f2hv(v[0], v[1])),  hv2u(f2hv(v[2], v[3])),
                      hv2u(f2hv(v[4], v[5])),  hv2u(f2hv(v[6], v[7])));
    m[1] = make_uint4(hv2u(f2hv(v[8], v[9])),  hv2u(f2hv(v[10], v[11])),
                      hv2u(f2hv(v[12], v[13])), hv2u(f2hv(v[14], v[15])));
}

__global__ __launch_bounds__(256) void k_edgeL1(
    const float4* __restrict__ edgeS, const int* __restrict__ s2d,
    RadialW ra, RadialW rb,
    const unsigned* __restrict__ UmA, const unsigned* __restrict__ UmB,
    unsigned short* __restrict__ msg /*stride 32*/, int nbE, int E) {
    int half = (blockIdx.x >= (unsigned)nbE) ? 1 : 0;
    int t = (blockIdx.x - half * nbE) * blockDim.x + threadIdx.x;
    if (t >= E) return;
    float4 a = edgeS[t];
    int sn = __float_as_int(a.w);
    RadialW rw = half ? rb : ra;
    const unsigned* __restrict__ Um = half ? UmB : UmA;
    hv2 hv[16];
    float v[16];
    radial_net_pk(a.x, a.y, a.z, rw, hv);
    contract_dot(hv, Um + (size_t)sn * 272, v);
    int td = s2d[t];
    uint4* m = (uint4*)(msg + (size_t)td * 32 + half * 16);
    m[0] = make_uint4(hv2u(f2hv(v[0], v[1])),  hv2u(f2hv(v[2], v[3])),
                      hv2u(f2hv(v[4], v[5])),  hv2u(f2hv(v[6], v[7])));
    m[1] = make_uint4(hv2u(f2hv(v[8], v[9])),  hv2u(f2hv(v[10], v[11])),
                      hv2u(f2hv(v[12], v[13])), hv2u(f2hv(v[14], v[15])));
}

// ---- segment reduces (contiguous, dst-sorted; x2 unrolled) ----------------
__global__ void k_reduce0(const unsigned short* __restrict__ msg,
                          const int* __restrict__ rowstart,
                          const float* __restrict__ h, const float* __restrict__ Wself,
                          float* __restrict__ out, int N) {
    int idx = blockIdx.x * blockDim.x + threadIdx.x;
    if (idx >= N * 16) return;
    int n = idx >> 4, o = idx & 15;
    int s = rowstart[n], t1 = rowstart[n + 1];
    float acc0 = 0.f, acc1 = 0.f;
    int t = s;
    for (; t + 1 < t1; t += 2) {
        acc0 += hbits2f(msg[(size_t)t * 16 + o]);
        acc1 += hbits2f(msg[(size_t)(t + 1) * 16 + o]);
    }
    if (t < t1) acc0 += hbits2f(msg[(size_t)t * 16 + o]);
    float acc = acc0 + acc1;
    int d = t1 - s;
    float invd = (d > 0) ? 1.f / (float)d : 0.f;
    float hi   = (d > 0) ? 1.f : 0.f;
    const float* __restrict__ hn = h + (size_t)n * 16;
    const float* __restrict__ w  = Wself + o * 16;
    float self = 0.f;
#pragma unroll
    for (int c = 0; c < 16; ++c) self += hn[c] * w[c];
    out[idx] = Y0C * acc * invd + hi * self;
}

__global__ void k_reduce1(const unsigned short* __restrict__ msg,  // stride 32
                          const uint2* __restrict__ y1d,
                          const int* __restrict__ rowstart,
                          const float* __restrict__ h, const float* __restrict__ Wself,
                          float* __restrict__ out0, float* __restrict__ out1, int N) {
    int idx = blockIdx.x * blockDim.x + threadIdx.x;
    if (idx >= N * 16) return;
    int n = idx >> 4, o = idx & 15;
    int s = rowstart[n], t1 = rowstart[n + 1];
    float a0 = 0.f, ax = 0.f, ay = 0.f, az = 0.f;
    float b0 = 0.f, bx = 0.f, by = 0.f, bz = 0.f;
    int t = s;
    for (; t + 1 < t1; t += 2) {
        const unsigned short* rowA = msg + (size_t)t * 32;
        const unsigned short* rowB = msg + (size_t)(t + 1) * 32;
        uint2 yva = y1d[t];
        uint2 yvb = y1d[t + 1];
        a0 += hbits2f(rowA[o]);
        b0 += hbits2f(rowB[o]);
        float pa = hbits2f(rowA[16 + o]);
        float pb = hbits2f(rowB[16 + o]);
        ax = fmaf(pa, hbits2f((unsigned short)yva.x), ax);
        ay = fmaf(pa, hbits2f((unsigned short)(yva.x >> 16)), ay);
        az = fmaf(pa, hbits2f((unsigned short)yva.y), az);
        bx = fmaf(pb, hbits2f((unsigned short)yvb.x), bx);
        by = fmaf(pb, hbits2f((unsigned short)(yvb.x >> 16)), by);
        bz = fmaf(pb, hbits2f((unsigned short)yvb.y), bz);
    }
    if (t < t1) {
        const unsigned short* rowA = msg + (size_t)t * 32;
        uint2 yva = y1d[t];
        a0 += hbits2f(rowA[o]);
        float pa = hbits2f(rowA[16 + o]);
        ax = fmaf(pa, hbits2f((unsigned short)yva.x), ax);
        ay = fmaf(pa, hbits2f((unsigned short)(yva.x >> 16)), ay);
        az = fmaf(pa, hbits2f((unsigned short)yva.y), az);
    }
    a0 += b0; ax += bx; ay += by; az += bz;
    int d = t1 - s;
    float invd = (d > 0) ? 1.f / (float)d : 0.f;
    float hi   = (d > 0) ? 1.f : 0.f;
    const float* __restrict__ hn = h + (size_t)n * 16;
    const float* __restrict__ w  = Wself + o * 16;
    float self = 0.f;
#pragma unroll
    for (int c = 0; c < 16; ++c) self += hn[c] * w[c];
    out0[idx] = Y0C * a0 * invd + hi * self;
    out1[(size_t)idx * 3]     = ax * invd;
    out1[(size_t)idx * 3 + 1] = ay * invd;
    out1[(size_t)idx * 3 + 2] = az * invd;
}

// ---------------------------------------------------------------------------
extern "C" void kernel_launch(void* const* d_in, const int* in_sizes, int n_in,
                              void* d_out, int out_size, void* d_ws, size_t ws_size,
                              hipStream_t stream) {
    (void)n_in; (void)out_size; (void)ws_size;
    const float* node_feats = (const float*)d_in[0];
    const float* pos    = (const float*)d_in[1];
    const float* edge_w = (const float*)d_in[2];
    const float* lin1_W = (const float*)d_in[3];
    const float* lin1_b = (const float*)d_in[4];
    const float* lin2_W = (const float*)d_in[5];
    const float* lin2_b = (const float*)d_in[6];
    const float* rW1    = (const float*)d_in[7];
    const float* rb1    = (const float*)d_in[8];
    const float* ln1_g  = (const float*)d_in[9];
    const float* ln1_b  = (const float*)d_in[10];
    const float* rW2    = (const float*)d_in[11];
    const float* rb2    = (const float*)d_in[12];
    const float* ln2_g  = (const float*)d_in[13];
    const float* ln2_b  = (const float*)d_in[14];
    const float* rW3    = (const float*)d_in[15];
    const float* rb3    = (const float*)d_in[16];
    const float* Wself  = (const float*)d_in[17];
    const int*   src    = (const int*)d_in[18];
    const int*   dst    = (const int*)d_in[19];

    const int N = in_sizes[1] / 3;     // pos is [N,3]
    const int E = in_sizes[18];        // src is [E]

    char* ws = (char*)d_ws;
    size_t off = 0;
    auto carve = [&](size_t bytes) -> char* {
        char* p = ws + off;
        off = (off + bytes + 255) & ~(size_t)255;
        return p;
    };
    float* h0   = (float*)carve((size_t)N * 16 * 4);
    float* h1   = (float*)carve((size_t)N * 16 * 4);
    int*   cntd = (int*)carve((size_t)N * 4);
    int*   cnts = (int*)carve((size_t)N * 4);
    int*   rsd  = (int*)carve((size_t)(N + 1) * 4);
    int*   rss  = (int*)carve((size_t)(N + 1) * 4);
    int*   s2d  = (int*)carve((size_t)E * 4);
    float4* edgeS = (float4*)carve((size_t)E * 16);
    uint2*  y1d   = (uint2*)carve((size_t)E * 8);
    unsigned* UaM = (unsigned*)carve((size_t)N * 272 * 4);  // Um + fused tail
    unsigned* UbM = (unsigned*)carve((size_t)N * 272 * 4);
    unsigned* Wp  = (unsigned*)carve((size_t)3 * 4608 * 4);
    unsigned* Wq  = (unsigned*)carve((size_t)3 * 512 * 4);
    unsigned short* msg = (unsigned short*)carve((size_t)E * 32 * 2);
    // disjoint-lifetime overlays inside msg (dead before edge kernels run):
    float* tmb = (float*)msg;                          // [N,67] embed temp (<8MB)
    int* posd = (int*)((char*)msg + (8u << 20));       // [E]
    int* poss = (int*)((char*)msg + (14u << 20));      // [E]

    auto nb = [](int n) { return (n + 255) / 256; };
    const int nbE = nb(E);
    const int nbU = (N + 31) / 32;
    const int nbE1 = nb(N * 67);
    const int nbC = nb((E + 1) / 2);
    int nbF1 = nbE1 + 9 + nbC;
    if (nbF1 < 4 * nbC) nbF1 = 4 * nbC;   // ensure all count slots exist

    // single fused memset (cntd and cnts are adjacent carves)
    hipMemsetAsync(cntd, 0, (size_t)((char*)cnts - (char*)cntd) + (size_t)N * 4, stream);

    // fuse1: embed1 || pack || count2 (interleaved every 4th block, 2 e/thr)
    k_fuse1<<<nbF1, 256, 0, stream>>>(node_feats, lin1_W, lin1_b, tmb, N,
                                      nbC, nbE1, rW3, rW2, Wp, Wq,
                                      src, dst, cntd, cnts, posd, poss, E);
    // fuse2: scan2 || embed2
    k_fuse2<<<2 + (N * 16 + 1023) / 1024, 1024, 0, stream>>>(
        cntd, rsd, cnts, rss, N, tmb, lin2_W, lin2_b, h0);
    // fuse3: u2-layer0 (every 3rd slot) || prep, interleaved
    k_fuse3<<<nbU + nbE, 256, 0, stream>>>(h0, Wp, rb3, UaM, nbU, N,
                                           pos, edge_w, src, dst, rsd, rss,
                                           posd, poss, edgeS, y1d, s2d, E);

    auto rnet = [&](int net, int ni) -> RadialW {
        RadialW r;
        r.W1 = rW1 + net * 96;   r.b1 = rb1 + net * 32;
        r.g1 = ln1_g + net * 32; r.gb1 = ln1_b + net * 32;
        r.b2 = rb2 + net * 32;
        r.g2 = ln2_g + net * 32; r.gb2 = ln2_b + net * 32;
        r.W2q = Wq + ni * 512;
        return r;
    };

    // ---- layer 0 (degree-1 branch dead: only net 0) ----
    k_edgeL0<<<nbE, 256, 0, stream>>>(edgeS, s2d, rnet(0, 0), UaM, msg, E);
    k_reduce0<<<nb(N * 16), 256, 0, stream>>>(msg, rsd, h0, Wself, h1, N);

    // ---- layer 1 (nets 2,3) ----
    k_u2<<<2 * nbU, 256, 0, stream>>>(h1, Wp, rb3 + 2 * 256, rb3 + 3 * 256,
                                      UaM, UbM, /*wpA=*/1, nbU, N);
    k_edgeL1<<<2 * nbE, 256, 0, stream>>>(edgeS, s2d, rnet(2, 1), rnet(3, 2),
                                          UaM, UbM, msg, nbE, E);
    float* out0 = (float*)d_out;
    float* out1 = (float*)d_out + (size_t)N * 16;
    k_reduce1<<<nb(N * 16), 256, 0, stream>>>(msg, y1d, rsd, h1, Wself + 256,
                                              out0, out1, N);
}

// Round 16
// 304.871 us; speedup vs baseline: 1.0398x; 1.0398x over previous
//
#include <hip/hip_runtime.h>
#include <hip/hip_fp16.h>

// ---------------------------------------------------------------------------
// SE3Transformer block. Round 16: partial revert of R15.
//   KEEP: fused-Ut node blocks (1088B: 16 f16-pair o-rows + f32 tail; edge
//         kernels gather ONE region/src — pushed edgeL1 below 51us),
//         fuse3 interleaved (u2-L0 every 3rd slot among prep).
//   REVERT: count role back to R14's 1 edge/thread (R15's 2-edge variant
//         halved count-block parallelism + raised VGPR 36->44: fuse1 48->52).
// Structure: fuse1 (count interleaved every 4th block || embed1 || pack),
// fuse2 (scan||embed2), fuse3 (u2-L0||prep interleaved), edgeL0, reduce0,
// u2-L1, edgeL1, reduce1. LN tree-reduce + fdot2 GEMM/contraction throughout.
// ---------------------------------------------------------------------------

#define Y0C 0.28209479177387814f
#define C1C 0.4886025119029199f

typedef _Float16 hv2 __attribute__((ext_vector_type(2)));

#if defined(__has_builtin)
#if __has_builtin(__builtin_amdgcn_fdot2)
#define FDOT2(a, b, c) __builtin_amdgcn_fdot2((a), (b), (c), false)
#endif
#endif
#ifndef FDOT2
#define FDOT2(a, b, c) ((c) + (float)(a).x * (float)(b).x + (float)(a).y * (float)(b).y)
#endif

static __device__ __forceinline__ unsigned h2u(__half2 h) {
    union { __half2 h; unsigned u; } x; x.h = h; return x.u;
}
static __device__ __forceinline__ __half2 u2h(unsigned u) {
    union { unsigned u; __half2 h; } x; x.u = u; return x.h;
}
static __device__ __forceinline__ hv2 u2hv(unsigned u) {
    union { unsigned u; hv2 h; } x; x.u = u; return x.h;
}
static __device__ __forceinline__ unsigned hv2u(hv2 h) {
    union { hv2 h; unsigned u; } x; x.h = h; return x.u;
}
static __device__ __forceinline__ hv2 f2hv(float a, float b) {
    hv2 r; r.x = (_Float16)a; r.y = (_Float16)b; return r;
}
static __device__ __forceinline__ float hbits2f(unsigned short s) {
    __half_raw r; r.x = s; return __half2float((__half)r);
}

struct RadialW {
    const float *W1, *b1, *g1, *gb1, *b2, *g2, *gb2;
    const unsigned* W2q;   // packed [j*16+kp] = half2(W2[2kp][j], W2[2kp+1][j])
};

// radial MLP: (x0,x1,x2) -> 32 (LN,relu) -> [fdot2 GEMM] -> 32 (LN,relu)
__device__ __forceinline__ void radial_net_pk(float x0, float x1, float x2,
                                              RadialW rw, hv2* hvpk /*[16]*/) {
    float h[32];
#pragma unroll
    for (int j = 0; j < 32; ++j)
        h[j] = rw.b1[j] + x0 * rw.W1[j] + x1 * rw.W1[32 + j] + x2 * rw.W1[64 + j];
    float s0 = 0.f, s1 = 0.f, s2 = 0.f, s3 = 0.f;
#pragma unroll
    for (int p = 0; p < 8; ++p) {
        s0 += h[4 * p]; s1 += h[4 * p + 1]; s2 += h[4 * p + 2]; s3 += h[4 * p + 3];
    }
    float mu = ((s0 + s1) + (s2 + s3)) * 0.03125f;
    float v0 = 0.f, v1 = 0.f, v2 = 0.f, v3 = 0.f;
#pragma unroll
    for (int p = 0; p < 8; ++p) {
        float d0 = h[4 * p] - mu, d1 = h[4 * p + 1] - mu;
        float d2 = h[4 * p + 2] - mu, d3 = h[4 * p + 3] - mu;
        v0 = fmaf(d0, d0, v0); v1 = fmaf(d1, d1, v1);
        v2 = fmaf(d2, d2, v2); v3 = fmaf(d3, d3, v3);
    }
    float var = ((v0 + v1) + (v2 + v3)) * 0.03125f;
    float rs = rsqrtf(var + 1e-5f);
#pragma unroll
    for (int j = 0; j < 32; ++j)
        h[j] = fmaxf((h[j] - mu) * rs * rw.g1[j] + rw.gb1[j], 0.f);

    hv2 hp[16];
#pragma unroll
    for (int p = 0; p < 16; ++p) hp[p] = f2hv(h[2 * p], h[2 * p + 1]);

    float h2[32];
#pragma unroll
    for (int j = 0; j < 32; ++j) {
        float acc = rw.b2[j];
        const unsigned* __restrict__ wj = rw.W2q + j * 16;   // uniform -> s_load
#pragma unroll
        for (int kp = 0; kp < 16; ++kp)
            acc = FDOT2(hp[kp], u2hv(wj[kp]), acc);
        h2[j] = acc;
    }
    s0 = s1 = s2 = s3 = 0.f;
#pragma unroll
    for (int p = 0; p < 8; ++p) {
        s0 += h2[4 * p]; s1 += h2[4 * p + 1]; s2 += h2[4 * p + 2]; s3 += h2[4 * p + 3];
    }
    mu = ((s0 + s1) + (s2 + s3)) * 0.03125f;
    v0 = v1 = v2 = v3 = 0.f;
#pragma unroll
    for (int p = 0; p < 8; ++p) {
        float d0 = h2[4 * p] - mu, d1 = h2[4 * p + 1] - mu;
        float d2 = h2[4 * p + 2] - mu, d3 = h2[4 * p + 3] - mu;
        v0 = fmaf(d0, d0, v0); v1 = fmaf(d1, d1, v1);
        v2 = fmaf(d2, d2, v2); v3 = fmaf(d3, d3, v3);
    }
    var = ((v0 + v1) + (v2 + v3)) * 0.03125f;
    rs = rsqrtf(var + 1e-5f);
    float y[32];
#pragma unroll
    for (int j = 0; j < 32; ++j)
        y[j] = fmaxf((h2[j] - mu) * rs * rw.g2[j] + rw.gb2[j], 0.f);
#pragma unroll
    for (int p = 0; p < 16; ++p) hvpk[p] = f2hv(y[2 * p], y[2 * p + 1]);
}

// v[o] = Ut[o] + sum_p dot2(hvpk[p], Um[o][p])
// Up = node block: 256 unsigned (16 o-rows of f16 pairs) + 16 f32 tail.
__device__ __forceinline__ void contract_dot(const hv2* hvpk,
                                             const unsigned* __restrict__ Up,
                                             float* v /*[16]*/) {
    const uint4* __restrict__ Um = (const uint4*)Up;
    const float* __restrict__ Ut = (const float*)(Up + 256);
    float4 t0 = ((const float4*)Ut)[0];
    float4 t1 = ((const float4*)Ut)[1];
    float4 t2 = ((const float4*)Ut)[2];
    float4 t3 = ((const float4*)Ut)[3];
    float tail[16] = {t0.x, t0.y, t0.z, t0.w, t1.x, t1.y, t1.z, t1.w,
                      t2.x, t2.y, t2.z, t2.w, t3.x, t3.y, t3.z, t3.w};
#pragma unroll
    for (int o = 0; o < 16; ++o) {
        uint4 q0 = Um[o * 4];
        uint4 q1 = Um[o * 4 + 1];
        uint4 q2 = Um[o * 4 + 2];
        uint4 q3 = Um[o * 4 + 3];
        float acc = tail[o];
        acc = FDOT2(hvpk[0],  u2hv(q0.x), acc);
        acc = FDOT2(hvpk[1],  u2hv(q0.y), acc);
        acc = FDOT2(hvpk[2],  u2hv(q0.z), acc);
        acc = FDOT2(hvpk[3],  u2hv(q0.w), acc);
        acc = FDOT2(hvpk[4],  u2hv(q1.x), acc);
        acc = FDOT2(hvpk[5],  u2hv(q1.y), acc);
        acc = FDOT2(hvpk[6],  u2hv(q1.z), acc);
        acc = FDOT2(hvpk[7],  u2hv(q1.w), acc);
        acc = FDOT2(hvpk[8],  u2hv(q2.x), acc);
        acc = FDOT2(hvpk[9],  u2hv(q2.y), acc);
        acc = FDOT2(hvpk[10], u2hv(q2.z), acc);
        acc = FDOT2(hvpk[11], u2hv(q2.w), acc);
        acc = FDOT2(hvpk[12], u2hv(q3.x), acc);
        acc = FDOT2(hvpk[13], u2hv(q3.y), acc);
        acc = FDOT2(hvpk[14], u2hv(q3.z), acc);
        acc = FDOT2(hvpk[15], u2hv(q3.w), acc);
        v[o] = acc;
    }
}

// ---- fuse1: embed1 || pack || count2 (count INTERLEAVED: every 4th block) -
__global__ __launch_bounds__(256) void k_fuse1(
    const float* __restrict__ nf, const float* __restrict__ W1,
    const float* __restrict__ b1, float* __restrict__ t, int N,
    int nbC, int nbEmb,
    const float* __restrict__ rW3, const float* __restrict__ rW2,
    unsigned* __restrict__ Wp, unsigned* __restrict__ Wq,
    const int* __restrict__ src, const int* __restrict__ dst,
    int* __restrict__ cntd, int* __restrict__ cnts,
    int* __restrict__ posd, int* __restrict__ poss, int E) {
    int b = blockIdx.x;
    int q = b >> 2;
    bool isCount = ((b & 3) == 3) && (q < nbC);
    if (isCount) {
        // ---- count2 role (1 edge/thread, R14 style) ----
        int e = q * 256 + threadIdx.x;
        if (e >= E) return;
        posd[e] = atomicAdd(cntd + dst[e], 1);
        poss[e] = atomicAdd(cnts + src[e], 1);
        return;
    }
    int dense = b - min(q, nbC);   // count blocks before b
    if (dense >= nbEmb) {
        // ---- pack role ----
        int tt = (dense - nbEmb) * 256 + threadIdx.x;
        if (tt < 3 * 256) {
            int ni = tt >> 8;
            int net = (ni == 0) ? 0 : ni + 1;
            int r = tt & 255;
            int i = r >> 4, o = r & 15;
            const float* __restrict__ W3n = rW3 + (size_t)net * 8192;
            unsigned* __restrict__ dp = Wp + (size_t)ni * 4608 + (size_t)(i * 16 + o) * 18;
#pragma unroll
            for (int kp = 0; kp < 16; ++kp) {
                float a = W3n[(2 * kp) * 256 + o * 16 + i];
                float bv = W3n[(2 * kp + 1) * 256 + o * 16 + i];
                dp[kp] = h2u(__floats2half2_rn(a, bv));
            }
        } else if (tt < 3 * 256 + 3 * 512) {
            int r = tt - 3 * 256;
            int ni = r / 512;
            int net = (ni == 0) ? 0 : ni + 1;
            int jk = r - ni * 512;
            int j = jk >> 4, kp = jk & 15;
            const float* __restrict__ W2n = rW2 + (size_t)net * 1024;
            Wq[ni * 512 + j * 16 + kp] =
                h2u(__floats2half2_rn(W2n[(2 * kp) * 32 + j],
                                      W2n[(2 * kp + 1) * 32 + j]));
        }
        return;
    }
    // ---- embed1 role ----
    int idx = dense * 256 + threadIdx.x;
    if (idx >= N * 67) return;
    int n = idx / 67, j = idx - n * 67;
    const float* __restrict__ x = nf + (size_t)n * 67;
    const float* __restrict__ w = W1 + j;
    float a0 = b1[j], a1 = 0.f, a2 = 0.f, a3 = 0.f;
#pragma unroll
    for (int i = 0; i < 64; i += 4) {
        a0 = fmaf(x[i],     w[(size_t)i * 67],       a0);
        a1 = fmaf(x[i + 1], w[(size_t)(i + 1) * 67], a1);
        a2 = fmaf(x[i + 2], w[(size_t)(i + 2) * 67], a2);
        a3 = fmaf(x[i + 3], w[(size_t)(i + 3) * 67], a3);
    }
    a0 = fmaf(x[64], w[64 * 67], a0);
    a1 = fmaf(x[65], w[65 * 67], a1);
    a2 = fmaf(x[66], w[66 * 67], a2);
    float s = (a0 + a1) + (a2 + a3);
    t[idx] = (s > 0.f) ? s : expm1f(s);   // ELU(alpha=1)
}

// ---- fuse2: scan2 (blocks 0,1) || embed2 (1024-thread blocks) -------------
__global__ __launch_bounds__(1024) void k_fuse2(
    const int* __restrict__ cntd, int* __restrict__ rsd,
    const int* __restrict__ cnts, int* __restrict__ rss, int N,
    const float* __restrict__ t, const float* __restrict__ W2,
    const float* __restrict__ b2, float* __restrict__ h0) {
    if (blockIdx.x < 2) {
        const int* __restrict__ c = (blockIdx.x == 0) ? cntd : cnts;
        int* __restrict__ rs      = (blockIdx.x == 0) ? rsd  : rss;
        int chunk = (N + 1023) >> 10;
        int lo = (int)threadIdx.x * chunk;
        int sum = 0;
        for (int j = 0; j < chunk; ++j) { int i = lo + j; sum += (i < N) ? c[i] : 0; }
        __shared__ int ps[1024];
        ps[threadIdx.x] = sum;
        __syncthreads();
        for (int off = 1; off < 1024; off <<= 1) {
            int v = (threadIdx.x >= (unsigned)off) ? ps[threadIdx.x - off] : 0;
            __syncthreads();
            ps[threadIdx.x] += v;
            __syncthreads();
        }
        int run = threadIdx.x ? ps[threadIdx.x - 1] : 0;
        if (threadIdx.x == 0) rs[0] = 0;
        for (int j = 0; j < chunk; ++j) {
            int i = lo + j;
            if (i < N) { run += c[i]; rs[i + 1] = run; }
        }
        return;
    }
    int idx = (blockIdx.x - 2) * 1024 + threadIdx.x;
    if (idx >= N * 16) return;
    int n = idx >> 4, c = idx & 15;
    const float* __restrict__ x = t + (size_t)n * 67;
    const float* __restrict__ w = W2 + c;
    float a0 = b2[c], a1 = 0.f, a2 = 0.f, a3 = 0.f;
#pragma unroll
    for (int i = 0; i < 64; i += 4) {
        a0 = fmaf(x[i],     w[(size_t)i * 16],       a0);
        a1 = fmaf(x[i + 1], w[(size_t)(i + 1) * 16], a1);
        a2 = fmaf(x[i + 2], w[(size_t)(i + 2) * 16], a2);
        a3 = fmaf(x[i + 3], w[(size_t)(i + 3) * 16], a3);
    }
    a0 = fmaf(x[64], w[64 * 16], a0);
    a1 = fmaf(x[65], w[65 * 16], a1);
    a2 = fmaf(x[66], w[66 * 16], a2);
    h0[idx] = (a0 + a1) + (a2 + a3);
}

// ---- u2 body (LDS-staged packed weights, 2 nodes/thread, fused-tail) ------
__device__ __forceinline__ void u2_body(
    unsigned* WL, int nbase, const float* __restrict__ h,
    const float* __restrict__ b3, unsigned* __restrict__ Um, int N) {
    int o = threadIdx.x & 15;
    int pr = threadIdx.x >> 4;
    int n0 = nbase + pr * 2;
    int n1 = n0 + 1;
    bool ok0 = n0 < N, ok1 = n1 < N;
    int m0 = ok0 ? n0 : 0, m1 = ok1 ? n1 : 0;

    const float* __restrict__ bo = b3 + o * 16;
    float tA = 0.f, tB = 0.f;
    __half2 hhA[16], hhB[16];
    {
        const float4* hp = (const float4*)(h + (size_t)m0 * 16);
#pragma unroll
        for (int q = 0; q < 4; ++q) {
            float4 hv = hp[q];
            tA += hv.x * bo[4 * q] + hv.y * bo[4 * q + 1]
                + hv.z * bo[4 * q + 2] + hv.w * bo[4 * q + 3];
            hhA[4 * q]     = __floats2half2_rn(hv.x, hv.x);
            hhA[4 * q + 1] = __floats2half2_rn(hv.y, hv.y);
            hhA[4 * q + 2] = __floats2half2_rn(hv.z, hv.z);
            hhA[4 * q + 3] = __floats2half2_rn(hv.w, hv.w);
        }
    }
    {
        const float4* hp = (const float4*)(h + (size_t)m1 * 16);
#pragma unroll
        for (int q = 0; q < 4; ++q) {
            float4 hv = hp[q];
            tB += hv.x * bo[4 * q] + hv.y * bo[4 * q + 1]
                + hv.z * bo[4 * q + 2] + hv.w * bo[4 * q + 3];
            hhB[4 * q]     = __floats2half2_rn(hv.x, hv.x);
            hhB[4 * q + 1] = __floats2half2_rn(hv.y, hv.y);
            hhB[4 * q + 2] = __floats2half2_rn(hv.z, hv.z);
            hhB[4 * q + 3] = __floats2half2_rn(hv.w, hv.w);
        }
    }

    __half2 accA[16], accB[16];
#pragma unroll
    for (int p = 0; p < 16; ++p) {
        accA[p] = __floats2half2_rn(0.f, 0.f);
        accB[p] = __floats2half2_rn(0.f, 0.f);
    }

#pragma unroll
    for (int i = 0; i < 16; ++i) {
        const uint2* __restrict__ row = (const uint2*)(WL + i * 288 + o * 18);
        __half2 ha = hhA[i], hb = hhB[i];
#pragma unroll
        for (int q = 0; q < 8; ++q) {
            uint2 w = row[q];
            accA[2 * q]     = __hfma2(ha, u2h(w.x), accA[2 * q]);
            accA[2 * q + 1] = __hfma2(ha, u2h(w.y), accA[2 * q + 1]);
            accB[2 * q]     = __hfma2(hb, u2h(w.x), accB[2 * q]);
            accB[2 * q + 1] = __hfma2(hb, u2h(w.y), accB[2 * q + 1]);
        }
    }

    if (ok0) {
        unsigned* base = Um + (size_t)n0 * 272;
        uint4* du = (uint4*)(base + o * 16);
#pragma unroll
        for (int q = 0; q < 4; ++q)
            du[q] = make_uint4(h2u(accA[4 * q]), h2u(accA[4 * q + 1]),
                               h2u(accA[4 * q + 2]), h2u(accA[4 * q + 3]));
        ((float*)(base + 256))[o] = tA;
    }
    if (ok1) {
        unsigned* base = Um + (size_t)n1 * 272;
        uint4* du = (uint4*)(base + o * 16);
#pragma unroll
        for (int q = 0; q < 4; ++q)
            du[q] = make_uint4(h2u(accB[4 * q]), h2u(accB[4 * q + 1]),
                               h2u(accB[4 * q + 2]), h2u(accB[4 * q + 3]));
        ((float*)(base + 256))[o] = tB;
    }
}

// ---- fuse3: u2-layer0 (every 3rd slot) || prep (interleaved) --------------
__global__ __launch_bounds__(256) void k_fuse3(
    const float* __restrict__ h, const unsigned* __restrict__ Wp,
    const float* __restrict__ b3, unsigned* __restrict__ Um, int nbU, int N,
    const float* __restrict__ pos, const float* __restrict__ ew,
    const int* __restrict__ src, const int* __restrict__ dst,
    const int* __restrict__ rsd, const int* __restrict__ rss,
    const int* __restrict__ posd, const int* __restrict__ poss,
    float4* __restrict__ edgeS, uint2* __restrict__ y1d,
    int* __restrict__ s2d, int E) {
    __shared__ unsigned WL[4608];
    int b = blockIdx.x;
    int k = b / 3;
    bool isU2 = ((b % 3) == 2) && (k < nbU);
    if (isU2) {
        for (int j = threadIdx.x; j < 4608; j += 256) WL[j] = Wp[j];  // net0
        __syncthreads();
        u2_body(WL, k * 32, h, b3, Um, N);
        return;
    }
    int dense = b - min(b / 3, nbU);
    int e = dense * 256 + threadIdx.x;
    if (e >= E) return;
    int s = src[e], d = dst[e];
    float dx = pos[3 * d]     - pos[3 * s];
    float dy = pos[3 * d + 1] - pos[3 * s + 1];
    float dz = pos[3 * d + 2] - pos[3 * s + 2];
    float r = sqrtf(dx * dx + dy * dy + dz * dz);
    float im = 1.f / fmaxf(r, 1e-8f);
    int ts = rss[s] + poss[e];
    int td = rsd[d] + posd[e];
    s2d[ts] = td;
    edgeS[ts] = make_float4(ew[2 * e], ew[2 * e + 1], r, __int_as_float(s));
    y1d[td] = make_uint2(h2u(__floats2half2_rn(C1C * dy * im, C1C * dz * im)),
                         h2u(__floats2half2_rn(C1C * dx * im, 0.f)));
}

// ---- u2 standalone (layer 1, 2 nets) --------------------------------------
__global__ __launch_bounds__(256) void k_u2(
    const float* __restrict__ h, const unsigned* __restrict__ Wp,
    const float* __restrict__ b3A, const float* __restrict__ b3B,
    unsigned* __restrict__ Um0, unsigned* __restrict__ Um1,
    int wpA, int nbPerNet, int N) {
    __shared__ unsigned WL[4608];
    int netSel = blockIdx.x / nbPerNet;
    int nbase = (blockIdx.x - netSel * nbPerNet) * 32;
    const unsigned* __restrict__ g = Wp + (size_t)(wpA + netSel) * 4608;
    for (int j = threadIdx.x; j < 4608; j += 256) WL[j] = g[j];
    __syncthreads();
    u2_body(WL, nbase, h, netSel ? b3B : b3A, netSel ? Um1 : Um0, N);
}

// ---- edge kernels (src-sorted traversal, scatter-write to dst slot) -------
__global__ __launch_bounds__(256) void k_edgeL0(
    const float4* __restrict__ edgeS, const int* __restrict__ s2d, RadialW ra,
    const unsigned* __restrict__ UmA,
    unsigned short* __restrict__ msg /*stride 16*/, int E) {
    int t = blockIdx.x * blockDim.x + threadIdx.x;
    if (t >= E) return;
    float4 a = edgeS[t];
    int sn = __float_as_int(a.w);
    hv2 hv[16];
    float v[16];
    radial_net_pk(a.x, a.y, a.z, ra, hv);
    contract_dot(hv, UmA + (size_t)sn * 272, v);
    int td = s2d[t];
    uint4* m = (uint4*)(msg + (size_t)td * 16);
    m[0] = make_uint4(hv2u(f2hv(v[0], v[1])),  hv2u(f2hv(v[2], v[3])),
                      hv2u(f2hv(v[4], v[5])),  hv2u(f2hv(v[6], v[7])));
    m[1] = make_uint4(hv2u(f2hv(v[8], v[9])),  hv2u(f2hv(v[10], v[11])),
                      hv2u(f2hv(v[12], v[13])), hv2u(f2hv(v[14], v[15])));
}

__global__ __launch_bounds__(256) void k_edgeL1(
    const float4* __restrict__ edgeS, const int* __restrict__ s2d,
    RadialW ra, RadialW rb,
    const unsigned* __restrict__ UmA, const unsigned* __restrict__ UmB,
    unsigned short* __restrict__ msg /*stride 32*/, int nbE, int E) {
    int half = (blockIdx.x >= (unsigned)nbE) ? 1 : 0;
    int t = (blockIdx.x - half * nbE) * blockDim.x + threadIdx.x;
    if (t >= E) return;
    float4 a = edgeS[t];
    int sn = __float_as_int(a.w);
    RadialW rw = half ? rb : ra;
    const unsigned* __restrict__ Um = half ? UmB : UmA;
    hv2 hv[16];
    float v[16];
    radial_net_pk(a.x, a.y, a.z, rw, hv);
    contract_dot(hv, Um + (size_t)sn * 272, v);
    int td = s2d[t];
    uint4* m = (uint4*)(msg + (size_t)td * 32 + half * 16);
    m[0] = make_uint4(hv2u(f2hv(v[0], v[1])),  hv2u(f2hv(v[2], v[3])),
                      hv2u(f2hv(v[4], v[5])),  hv2u(f2hv(v[6], v[7])));
    m[1] = make_uint4(hv2u(f2hv(v[8], v[9])),  hv2u(f2hv(v[10], v[11])),
                      hv2u(f2hv(v[12], v[13])), hv2u(f2hv(v[14], v[15])));
}

// ---- segment reduces (contiguous, dst-sorted; x2 unrolled) ----------------
__global__ void k_reduce0(const unsigned short* __restrict__ msg,
                          const int* __restrict__ rowstart,
                          const float* __restrict__ h, const float* __restrict__ Wself,
                          float* __restrict__ out, int N) {
    int idx = blockIdx.x * blockDim.x + threadIdx.x;
    if (idx >= N * 16) return;
    int n = idx >> 4, o = idx & 15;
    int s = rowstart[n], t1 = rowstart[n + 1];
    float acc0 = 0.f, acc1 = 0.f;
    int t = s;
    for (; t + 1 < t1; t += 2) {
        acc0 += hbits2f(msg[(size_t)t * 16 + o]);
        acc1 += hbits2f(msg[(size_t)(t + 1) * 16 + o]);
    }
    if (t < t1) acc0 += hbits2f(msg[(size_t)t * 16 + o]);
    float acc = acc0 + acc1;
    int d = t1 - s;
    float invd = (d > 0) ? 1.f / (float)d : 0.f;
    float hi   = (d > 0) ? 1.f : 0.f;
    const float* __restrict__ hn = h + (size_t)n * 16;
    const float* __restrict__ w  = Wself + o * 16;
    float self = 0.f;
#pragma unroll
    for (int c = 0; c < 16; ++c) self += hn[c] * w[c];
    out[idx] = Y0C * acc * invd + hi * self;
}

__global__ void k_reduce1(const unsigned short* __restrict__ msg,  // stride 32
                          const uint2* __restrict__ y1d,
                          const int* __restrict__ rowstart,
                          const float* __restrict__ h, const float* __restrict__ Wself,
                          float* __restrict__ out0, float* __restrict__ out1, int N) {
    int idx = blockIdx.x * blockDim.x + threadIdx.x;
    if (idx >= N * 16) return;
    int n = idx >> 4, o = idx & 15;
    int s = rowstart[n], t1 = rowstart[n + 1];
    float a0 = 0.f, ax = 0.f, ay = 0.f, az = 0.f;
    float b0 = 0.f, bx = 0.f, by = 0.f, bz = 0.f;
    int t = s;
    for (; t + 1 < t1; t += 2) {
        const unsigned short* rowA = msg + (size_t)t * 32;
        const unsigned short* rowB = msg + (size_t)(t + 1) * 32;
        uint2 yva = y1d[t];
        uint2 yvb = y1d[t + 1];
        a0 += hbits2f(rowA[o]);
        b0 += hbits2f(rowB[o]);
        float pa = hbits2f(rowA[16 + o]);
        float pb = hbits2f(rowB[16 + o]);
        ax = fmaf(pa, hbits2f((unsigned short)yva.x), ax);
        ay = fmaf(pa, hbits2f((unsigned short)(yva.x >> 16)), ay);
        az = fmaf(pa, hbits2f((unsigned short)yva.y), az);
        bx = fmaf(pb, hbits2f((unsigned short)yvb.x), bx);
        by = fmaf(pb, hbits2f((unsigned short)(yvb.x >> 16)), by);
        bz = fmaf(pb, hbits2f((unsigned short)yvb.y), bz);
    }
    if (t < t1) {
        const unsigned short* rowA = msg + (size_t)t * 32;
        uint2 yva = y1d[t];
        a0 += hbits2f(rowA[o]);
        float pa = hbits2f(rowA[16 + o]);
        ax = fmaf(pa, hbits2f((unsigned short)yva.x), ax);
        ay = fmaf(pa, hbits2f((unsigned short)(yva.x >> 16)), ay);
        az = fmaf(pa, hbits2f((unsigned short)yva.y), az);
    }
    a0 += b0; ax += bx; ay += by; az += bz;
    int d = t1 - s;
    float invd = (d > 0) ? 1.f / (float)d : 0.f;
    float hi   = (d > 0) ? 1.f : 0.f;
    const float* __restrict__ hn = h + (size_t)n * 16;
    const float* __restrict__ w  = Wself + o * 16;
    float self = 0.f;
#pragma unroll
    for (int c = 0; c < 16; ++c) self += hn[c] * w[c];
    out0[idx] = Y0C * a0 * invd + hi * self;
    out1[(size_t)idx * 3]     = ax * invd;
    out1[(size_t)idx * 3 + 1] = ay * invd;
    out1[(size_t)idx * 3 + 2] = az * invd;
}

// ---------------------------------------------------------------------------
extern "C" void kernel_launch(void* const* d_in, const int* in_sizes, int n_in,
                              void* d_out, int out_size, void* d_ws, size_t ws_size,
                              hipStream_t stream) {
    (void)n_in; (void)out_size; (void)ws_size;
    const float* node_feats = (const float*)d_in[0];
    const float* pos    = (const float*)d_in[1];
    const float* edge_w = (const float*)d_in[2];
    const float* lin1_W = (const float*)d_in[3];
    const float* lin1_b = (const float*)d_in[4];
    const float* lin2_W = (const float*)d_in[5];
    const float* lin2_b = (const float*)d_in[6];
    const float* rW1    = (const float*)d_in[7];
    const float* rb1    = (const float*)d_in[8];
    const float* ln1_g  = (const float*)d_in[9];
    const float* ln1_b  = (const float*)d_in[10];
    const float* rW2    = (const float*)d_in[11];
    const float* rb2    = (const float*)d_in[12];
    const float* ln2_g  = (const float*)d_in[13];
    const float* ln2_b  = (const float*)d_in[14];
    const float* rW3    = (const float*)d_in[15];
    const float* rb3    = (const float*)d_in[16];
    const float* Wself  = (const float*)d_in[17];
    const int*   src    = (const int*)d_in[18];
    const int*   dst    = (const int*)d_in[19];

    const int N = in_sizes[1] / 3;     // pos is [N,3]
    const int E = in_sizes[18];        // src is [E]

    char* ws = (char*)d_ws;
    size_t off = 0;
    auto carve = [&](size_t bytes) -> char* {
        char* p = ws + off;
        off = (off + bytes + 255) & ~(size_t)255;
        return p;
    };
    float* h0   = (float*)carve((size_t)N * 16 * 4);
    float* h1   = (float*)carve((size_t)N * 16 * 4);
    int*   cntd = (int*)carve((size_t)N * 4);
    int*   cnts = (int*)carve((size_t)N * 4);
    int*   rsd  = (int*)carve((size_t)(N + 1) * 4);
    int*   rss  = (int*)carve((size_t)(N + 1) * 4);
    int*   s2d  = (int*)carve((size_t)E * 4);
    float4* edgeS = (float4*)carve((size_t)E * 16);
    uint2*  y1d   = (uint2*)carve((size_t)E * 8);
    unsigned* UaM = (unsigned*)carve((size_t)N * 272 * 4);  // Um + fused tail
    unsigned* UbM = (unsigned*)carve((size_t)N * 272 * 4);
    unsigned* Wp  = (unsigned*)carve((size_t)3 * 4608 * 4);
    unsigned* Wq  = (unsigned*)carve((size_t)3 * 512 * 4);
    unsigned short* msg = (unsigned short*)carve((size_t)E * 32 * 2);
    // disjoint-lifetime overlays inside msg (dead before edge kernels run):
    float* tmb = (float*)msg;                          // [N,67] embed temp (<8MB)
    int* posd = (int*)((char*)msg + (8u << 20));       // [E]
    int* poss = (int*)((char*)msg + (14u << 20));      // [E]

    auto nb = [](int n) { return (n + 255) / 256; };
    const int nbE = nb(E);
    const int nbU = (N + 31) / 32;
    const int nbE1 = nb(N * 67);
    const int nbC = nbE;
    int nbF1 = nbE1 + 9 + nbC;
    if (nbF1 < 4 * nbC) nbF1 = 4 * nbC;   // ensure all count slots exist

    // single fused memset (cntd and cnts are adjacent carves)
    hipMemsetAsync(cntd, 0, (size_t)((char*)cnts - (char*)cntd) + (size_t)N * 4, stream);

    // fuse1: embed1 || pack || count2 (count interleaved every 4th block)
    k_fuse1<<<nbF1, 256, 0, stream>>>(node_feats, lin1_W, lin1_b, tmb, N,
                                      nbC, nbE1, rW3, rW2, Wp, Wq,
                                      src, dst, cntd, cnts, posd, poss, E);
    // fuse2: scan2 || embed2
    k_fuse2<<<2 + (N * 16 + 1023) / 1024, 1024, 0, stream>>>(
        cntd, rsd, cnts, rss, N, tmb, lin2_W, lin2_b, h0);
    // fuse3: u2-layer0 (every 3rd slot) || prep, interleaved
    k_fuse3<<<nbU + nbE, 256, 0, stream>>>(h0, Wp, rb3, UaM, nbU, N,
                                           pos, edge_w, src, dst, rsd, rss,
                                           posd, poss, edgeS, y1d, s2d, E);

    auto rnet = [&](int net, int ni) -> RadialW {
        RadialW r;
        r.W1 = rW1 + net * 96;   r.b1 = rb1 + net * 32;
        r.g1 = ln1_g + net * 32; r.gb1 = ln1_b + net * 32;
        r.b2 = rb2 + net * 32;
        r.g2 = ln2_g + net * 32; r.gb2 = ln2_b + net * 32;
        r.W2q = Wq + ni * 512;
        return r;
    };

    // ---- layer 0 (degree-1 branch dead: only net 0) ----
    k_edgeL0<<<nbE, 256, 0, stream>>>(edgeS, s2d, rnet(0, 0), UaM, msg, E);
    k_reduce0<<<nb(N * 16), 256, 0, stream>>>(msg, rsd, h0, Wself, h1, N);

    // ---- layer 1 (nets 2,3) ----
    k_u2<<<2 * nbU, 256, 0, stream>>>(h1, Wp, rb3 + 2 * 256, rb3 + 3 * 256,
                                      UaM, UbM, /*wpA=*/1, nbU, N);
    k_edgeL1<<<2 * nbE, 256, 0, stream>>>(edgeS, s2d, rnet(2, 1), rnet(3, 2),
                                          UaM, UbM, msg, nbE, E);
    float* out0 = (float*)d_out;
    float* out1 = (float*)d_out + (size_t)N * 16;
    k_reduce1<<<nb(N * 16), 256, 0, stream>>>(msg, y1d, rsd, h1, Wself + 256,
                                              out0, out1, N);
}